// Round 3
// baseline (123.659 us; speedup 1.0000x reference)
//
#include <hip/hip_runtime.h>
#include <math.h>

#define IGNORE_INDEX (-100)
#define EPS 1e-10f

// ---------------------------------------------------------------------------
// ws layout (doubles): ws[0] = sum of per-row terms, ws[1] = n_valid
// ---------------------------------------------------------------------------

__global__ void ce_init_ws(double* ws) {
    if (threadIdx.x < 2) ws[threadIdx.x] = 0.0;
}

// ---- helpers --------------------------------------------------------------

template<int CHUNKS>
__device__ __forceinline__ void load_row(const float* __restrict__ pred,
                                         int row, int lane, int tclamped,
                                         float4* v, float& pt) {
    constexpr int C = CHUNKS * 256;
    const float*  rp  = pred + (size_t)row * C;
    const float4* rp4 = (const float4*)rp;
    #pragma unroll
    for (int j = 0; j < CHUNKS; ++j)
        v[j] = rp4[lane + j * 64];       // lane-contiguous 16B -> coalesced
    pt = rp[tclamped];                   // uniform-address gather, 1 dword
}

template<int CHUNKS>
__device__ __forceinline__ void compute_row(const float4* v, float pt,
                                            int t, float kn, float un, int lane,
                                            double& localSum, double& localCnt) {
    // row max
    float m = -INFINITY;
    #pragma unroll
    for (int j = 0; j < CHUNKS; ++j)
        m = fmaxf(m, fmaxf(fmaxf(v[j].x, v[j].y), fmaxf(v[j].z, v[j].w)));
    #pragma unroll
    for (int off = 32; off >= 1; off >>= 1)
        m = fmaxf(m, __shfl_xor(m, off, 64));

    // sum exp(x - m)
    float s = 0.0f;
    #pragma unroll
    for (int j = 0; j < CHUNKS; ++j) {
        s += __expf(v[j].x - m);
        s += __expf(v[j].y - m);
        s += __expf(v[j].z - m);
        s += __expf(v[j].w - m);
    }
    #pragma unroll
    for (int off = 32; off >= 1; off >>= 1)
        s += __shfl_xor(s, off, 64);

    const float logp = pt - m - __logf(s);
    const float p    = __expf(logp);
    const float term = logp * kn + __logf(1.0f - p + EPS) * un;

    if (lane == 0 && t != IGNORE_INDEX) {
        localSum += (double)term;
        localCnt += 1.0;
    }
}

// Fast path: one wave per row, 2-row software pipeline.
// While row r's reduce/epilogue runs, row r+2's streaming loads (+ target
// gather) are already in flight -> memory pipe never idles on epilogues.
// Scalars (tgt/known/unknown) prefetched 2 iterations ahead so the gather
// address is ready at load-issue time.
template<int CHUNKS>
__global__ __launch_bounds__(256) void ce_ul_main(
    const float* __restrict__ pred,
    const int*   __restrict__ tgt,
    const float* __restrict__ known,
    const float* __restrict__ unknown,
    double*      __restrict__ ws,
    int N)
{
    const int lane          = threadIdx.x & 63;
    const int wave          = threadIdx.x >> 6;
    const int wavesPerBlock = blockDim.x >> 6;
    const int gwave         = blockIdx.x * wavesPerBlock + wave;
    const int nw            = gridDim.x * wavesPerBlock;

    double localSum = 0.0;
    double localCnt = 0.0;

    // ---- prologue: scalar slots for rows r, r+nw (current) and r+2nw, r+3nw
    int   tA = 0, tB = 0, tC = 0, tD = 0;
    float knA = 0, unA = 0, knB = 0, unB = 0, knC = 0, unC = 0, knD = 0, unD = 0;

    const int rA0 = gwave, rB0 = gwave + nw, rC0 = gwave + 2 * nw, rD0 = gwave + 3 * nw;
    if (rA0 < N) { tA = tgt[rA0]; knA = known[rA0]; unA = unknown[rA0]; }
    if (rB0 < N) { tB = tgt[rB0]; knB = known[rB0]; unB = unknown[rB0]; }
    if (rC0 < N) { tC = tgt[rC0]; knC = known[rC0]; unC = unknown[rC0]; }
    if (rD0 < N) { tD = tgt[rD0]; knD = known[rD0]; unD = unknown[rD0]; }

    float4 vA[CHUNKS]; float ptA = 0.0f;
    float4 vB[CHUNKS]; float ptB = 0.0f;
    if (rA0 < N) load_row<CHUNKS>(pred, rA0, lane, (tA < 0) ? 0 : tA, vA, ptA);
    if (rB0 < N) load_row<CHUNKS>(pred, rB0, lane, (tB < 0) ? 0 : tB, vB, ptB);

    for (int r = gwave; r < N; r += 2 * nw) {
        const int r2 = r + 2 * nw;   // next A row
        const int r3 = r + 3 * nw;   // next B row
        const int r4 = r + 4 * nw;   // scalar prefetch targets
        const int r5 = r + 5 * nw;

        // ---- compute A (row r); then immediately refill A for r2 ----
        compute_row<CHUNKS>(vA, ptA, tA, knA, unA, lane, localSum, localCnt);
        tA = tC; knA = knC; unA = unC;
        if (r2 < N) load_row<CHUNKS>(pred, r2, lane, (tA < 0) ? 0 : tA, vA, ptA);
        if (r4 < N) { tC = tgt[r4]; knC = known[r4]; unC = unknown[r4]; }

        // ---- compute B (row r+nw); then refill B for r3 ----
        if (r + nw < N)
            compute_row<CHUNKS>(vB, ptB, tB, knB, unB, lane, localSum, localCnt);
        tB = tD; knB = knD; unB = unD;
        if (r3 < N) load_row<CHUNKS>(pred, r3, lane, (tB < 0) ? 0 : tB, vB, ptB);
        if (r5 < N) { tD = tgt[r5]; knD = known[r5]; unD = unknown[r5]; }
    }

    __shared__ double sSum[8];
    __shared__ double sCnt[8];
    if (lane == 0) { sSum[wave] = localSum; sCnt[wave] = localCnt; }
    __syncthreads();
    if (threadIdx.x == 0) {
        double t = 0.0, c = 0.0;
        for (int i = 0; i < wavesPerBlock; ++i) { t += sSum[i]; c += sCnt[i]; }
        atomicAdd(&ws[0], t);
        atomicAdd(&ws[1], c);
    }
}

// Generic fallback for arbitrary C (two passes over the row; L1/L2-backed).
__global__ __launch_bounds__(256) void ce_ul_generic(
    const float* __restrict__ pred,
    const int*   __restrict__ tgt,
    const float* __restrict__ known,
    const float* __restrict__ unknown,
    double*      __restrict__ ws,
    int N, int C)
{
    const int lane          = threadIdx.x & 63;
    const int wave          = threadIdx.x >> 6;
    const int wavesPerBlock = blockDim.x >> 6;
    const int gwave         = blockIdx.x * wavesPerBlock + wave;
    const int nwaves        = gridDim.x * wavesPerBlock;

    double localSum = 0.0;
    double localCnt = 0.0;

    for (int row = gwave; row < N; row += nwaves) {
        const float* rp = pred + (size_t)row * C;
        float m = -INFINITY;
        for (int c = lane; c < C; c += 64) m = fmaxf(m, rp[c]);
        for (int off = 32; off >= 1; off >>= 1)
            m = fmaxf(m, __shfl_xor(m, off, 64));
        float s = 0.0f;
        for (int c = lane; c < C; c += 64) s += __expf(rp[c] - m);
        for (int off = 32; off >= 1; off >>= 1)
            s += __shfl_xor(s, off, 64);
        if (lane == 0) {
            int t = tgt[row];
            if (t != IGNORE_INDEX) {
                float pt   = rp[t];
                float logp = pt - m - __logf(s);
                float p    = __expf(logp);
                float term = logp * known[row]
                           + __logf(1.0f - p + EPS) * unknown[row];
                localSum += (double)term;
                localCnt += 1.0;
            }
        }
    }

    __shared__ double sSum[8];
    __shared__ double sCnt[8];
    if (lane == 0) { sSum[wave] = localSum; sCnt[wave] = localCnt; }
    __syncthreads();
    if (threadIdx.x == 0) {
        double t = 0.0, c = 0.0;
        for (int i = 0; i < wavesPerBlock; ++i) { t += sSum[i]; c += sCnt[i]; }
        atomicAdd(&ws[0], t);
        atomicAdd(&ws[1], c);
    }
}

__global__ void ce_ul_final(const double* __restrict__ ws, float* __restrict__ out) {
    if (threadIdx.x == 0) out[0] = (float)(-ws[0] / ws[1]);
}

extern "C" void kernel_launch(void* const* d_in, const int* in_sizes, int n_in,
                              void* d_out, int out_size, void* d_ws, size_t ws_size,
                              hipStream_t stream) {
    const float* pred    = (const float*)d_in[0];
    const int*   tgt     = (const int*)d_in[1];
    const float* known   = (const float*)d_in[2];
    const float* unknown = (const float*)d_in[3];
    float*       out     = (float*)d_out;
    double*      ws      = (double*)d_ws;

    const int N = in_sizes[1];
    const int C = in_sizes[0] / N;

    hipLaunchKernelGGL(ce_init_ws, dim3(1), dim3(64), 0, stream, ws);

    const int blocks = 2048;   // 8192 waves, grid-stride over N rows
    if (C == 1024) {
        hipLaunchKernelGGL((ce_ul_main<4>), dim3(blocks), dim3(256), 0, stream,
                           pred, tgt, known, unknown, ws, N);
    } else {
        hipLaunchKernelGGL(ce_ul_generic, dim3(blocks), dim3(256), 0, stream,
                           pred, tgt, known, unknown, ws, N, C);
    }

    hipLaunchKernelGGL(ce_ul_final, dim3(1), dim3(64), 0, stream, ws, out);
}

// Round 4
// 100.598 us; speedup vs baseline: 1.2292x; 1.2292x over previous
//
#include <hip/hip_runtime.h>
#include <math.h>

#define IGNORE_INDEX (-100)
#define EPS 1e-10f

// ---------------------------------------------------------------------------
// ws layout: per-block partials, 2 doubles each: ws[2*b] = sum, ws[2*b+1] = cnt.
// No initialization kernel needed: every block writes its slot unconditionally,
// and the final kernel reads exactly nblocks slots. No atomics anywhere.
// ---------------------------------------------------------------------------

// Fast path: C == CHUNKS*256, one wave per row, row resident in registers.
//  - row loads + uniform target-gather issued together (latency co-hidden)
//  - tgt/known/unknown prefetched one row ahead
//  - per-block (sum,cnt) written non-atomically to a private ws slot
template<int CHUNKS>
__global__ __launch_bounds__(256) void ce_ul_main(
    const float* __restrict__ pred,
    const int*   __restrict__ tgt,
    const float* __restrict__ known,
    const float* __restrict__ unknown,
    double*      __restrict__ ws,
    int N)
{
    constexpr int C = CHUNKS * 256;
    const int lane  = threadIdx.x & 63;
    const int wave  = threadIdx.x >> 6;
    const int wpb   = blockDim.x >> 6;
    const int gwave = blockIdx.x * wpb + wave;
    const int nw    = gridDim.x * wpb;

    double localSum = 0.0;
    double localCnt = 0.0;

    // prefetch first row's scalars
    int   t_nxt = 0; float kn_nxt = 0.0f, un_nxt = 0.0f;
    if (gwave < N) { t_nxt = tgt[gwave]; kn_nxt = known[gwave]; un_nxt = unknown[gwave]; }

    for (int row = gwave; row < N; row += nw) {
        const int   t  = t_nxt;
        const float kn = kn_nxt;
        const float un = un_nxt;

        const float*  rp  = pred + (size_t)row * C;
        const float4* rp4 = (const float4*)rp;

        float4 v[CHUNKS];
        #pragma unroll
        for (int j = 0; j < CHUNKS; ++j)
            v[j] = rp4[lane + j * 64];        // lane-contiguous 16B -> coalesced
        const float pt = rp[(t < 0) ? 0 : t]; // uniform gather, issued with row

        // prefetch next row's scalars (latency hides under this row's compute)
        const int nrow = row + nw;
        if (nrow < N) { t_nxt = tgt[nrow]; kn_nxt = known[nrow]; un_nxt = unknown[nrow]; }

        // row max
        float m = -INFINITY;
        #pragma unroll
        for (int j = 0; j < CHUNKS; ++j)
            m = fmaxf(m, fmaxf(fmaxf(v[j].x, v[j].y), fmaxf(v[j].z, v[j].w)));
        #pragma unroll
        for (int off = 32; off >= 1; off >>= 1)
            m = fmaxf(m, __shfl_xor(m, off, 64));

        // sum exp(x - m)
        float s = 0.0f;
        #pragma unroll
        for (int j = 0; j < CHUNKS; ++j) {
            s += __expf(v[j].x - m);
            s += __expf(v[j].y - m);
            s += __expf(v[j].z - m);
            s += __expf(v[j].w - m);
        }
        #pragma unroll
        for (int off = 32; off >= 1; off >>= 1)
            s += __shfl_xor(s, off, 64);

        const float logp = pt - m - __logf(s);
        const float p    = __expf(logp);
        const float term = logp * kn + __logf(1.0f - p + EPS) * un;

        if (lane == 0 && t != IGNORE_INDEX) {
            localSum += (double)term;
            localCnt += 1.0;
        }
    }

    // block reduce (only lane 0 of each wave holds nonzero) -> private ws slot
    __shared__ double sS[8];
    __shared__ double sC[8];
    if (lane == 0) { sS[wave] = localSum; sC[wave] = localCnt; }
    __syncthreads();
    if (threadIdx.x == 0) {
        double a = 0.0, b = 0.0;
        for (int i = 0; i < wpb; ++i) { a += sS[i]; b += sC[i]; }
        ws[2 * blockIdx.x]     = a;   // plain stores, no atomics
        ws[2 * blockIdx.x + 1] = b;
    }
}

// Generic fallback for arbitrary C (two passes over the row; L1/L2-backed).
__global__ __launch_bounds__(256) void ce_ul_generic(
    const float* __restrict__ pred,
    const int*   __restrict__ tgt,
    const float* __restrict__ known,
    const float* __restrict__ unknown,
    double*      __restrict__ ws,
    int N, int C)
{
    const int lane  = threadIdx.x & 63;
    const int wave  = threadIdx.x >> 6;
    const int wpb   = blockDim.x >> 6;
    const int gwave = blockIdx.x * wpb + wave;
    const int nw    = gridDim.x * wpb;

    double localSum = 0.0;
    double localCnt = 0.0;

    for (int row = gwave; row < N; row += nw) {
        const float* rp = pred + (size_t)row * C;
        float m = -INFINITY;
        for (int c = lane; c < C; c += 64) m = fmaxf(m, rp[c]);
        for (int off = 32; off >= 1; off >>= 1)
            m = fmaxf(m, __shfl_xor(m, off, 64));
        float s = 0.0f;
        for (int c = lane; c < C; c += 64) s += __expf(rp[c] - m);
        for (int off = 32; off >= 1; off >>= 1)
            s += __shfl_xor(s, off, 64);
        int t = tgt[row];
        if (lane == 0 && t != IGNORE_INDEX) {
            float pt   = rp[t];
            float logp = pt - m - __logf(s);
            float p    = __expf(logp);
            float term = logp * known[row] + __logf(1.0f - p + EPS) * unknown[row];
            localSum += (double)term;
            localCnt += 1.0;
        }
    }

    __shared__ double sS[8];
    __shared__ double sC[8];
    if (lane == 0) { sS[wave] = localSum; sC[wave] = localCnt; }
    __syncthreads();
    if (threadIdx.x == 0) {
        double a = 0.0, b = 0.0;
        for (int i = 0; i < wpb; ++i) { a += sS[i]; b += sC[i]; }
        ws[2 * blockIdx.x]     = a;
        ws[2 * blockIdx.x + 1] = b;
    }
}

// Single-block final reduce of per-block partials.
__global__ __launch_bounds__(256) void ce_ul_final(const double* __restrict__ ws,
                                                   float* __restrict__ out,
                                                   int nblocks)
{
    const int tid = threadIdx.x;
    double a = 0.0, b = 0.0;
    for (int i = tid; i < nblocks; i += 256) {
        a += ws[2 * i];
        b += ws[2 * i + 1];
    }
    for (int off = 32; off >= 1; off >>= 1) {
        a += __shfl_xor(a, off, 64);
        b += __shfl_xor(b, off, 64);
    }
    __shared__ double sA[4];
    __shared__ double sB[4];
    const int lane = tid & 63, wave = tid >> 6;
    if (lane == 0) { sA[wave] = a; sB[wave] = b; }
    __syncthreads();
    if (tid == 0) {
        double ta = sA[0] + sA[1] + sA[2] + sA[3];
        double tb = sB[0] + sB[1] + sB[2] + sB[3];
        out[0] = (float)(-ta / tb);
    }
}

extern "C" void kernel_launch(void* const* d_in, const int* in_sizes, int n_in,
                              void* d_out, int out_size, void* d_ws, size_t ws_size,
                              hipStream_t stream) {
    const float* pred    = (const float*)d_in[0];
    const int*   tgt     = (const int*)d_in[1];
    const float* known   = (const float*)d_in[2];
    const float* unknown = (const float*)d_in[3];
    float*       out     = (float*)d_out;
    double*      ws      = (double*)d_ws;

    const int N = in_sizes[1];
    const int C = in_sizes[0] / N;

    const int blocks = 2048;   // 8192 waves, grid-stride over N rows
    if (C == 1024) {
        hipLaunchKernelGGL((ce_ul_main<4>), dim3(blocks), dim3(256), 0, stream,
                           pred, tgt, known, unknown, ws, N);
    } else {
        hipLaunchKernelGGL(ce_ul_generic, dim3(blocks), dim3(256), 0, stream,
                           pred, tgt, known, unknown, ws, N, C);
    }

    hipLaunchKernelGGL(ce_ul_final, dim3(1), dim3(256), 0, stream,
                       ws, out, blocks);
}

// Round 6
// 90.104 us; speedup vs baseline: 1.3724x; 1.1165x over previous
//
#include <hip/hip_runtime.h>
#include <math.h>

#define IGNORE_INDEX (-100)
#define EPS 1e-10f

// clang-native vector type: __builtin_nontemporal_load requires a pointer to
// scalar or native vector (HIP_vector_type<float,4> is a struct -> rejected).
typedef float floatx4 __attribute__((ext_vector_type(4)));

// ---------------------------------------------------------------------------
// ws layout: per-block partials, 2 doubles each: ws[2*b] = sum, ws[2*b+1] = cnt.
// Every block writes its slot unconditionally -> no init kernel, no atomics.
// ---------------------------------------------------------------------------

// Fast path: C == CHUNKS*256, one wave per row, row resident in registers.
//  - pred streamed with NONTEMPORAL loads (zero reuse -> bypass LLC fill)
//  - row loads + uniform target-gather issued together (latency co-hidden)
//  - tgt/known/unknown prefetched one row ahead (cached path)
//  - per-block (sum,cnt) written non-atomically to a private ws slot
template<int CHUNKS>
__global__ __launch_bounds__(256) void ce_ul_main(
    const float* __restrict__ pred,
    const int*   __restrict__ tgt,
    const float* __restrict__ known,
    const float* __restrict__ unknown,
    double*      __restrict__ ws,
    int N)
{
    constexpr int C = CHUNKS * 256;
    const int lane  = threadIdx.x & 63;
    const int wave  = threadIdx.x >> 6;
    const int wpb   = blockDim.x >> 6;
    const int gwave = blockIdx.x * wpb + wave;
    const int nw    = gridDim.x * wpb;

    double localSum = 0.0;
    double localCnt = 0.0;

    // prefetch first row's scalars
    int   t_nxt = 0; float kn_nxt = 0.0f, un_nxt = 0.0f;
    if (gwave < N) { t_nxt = tgt[gwave]; kn_nxt = known[gwave]; un_nxt = unknown[gwave]; }

    for (int row = gwave; row < N; row += nw) {
        const int   t  = t_nxt;
        const float kn = kn_nxt;
        const float un = un_nxt;

        const float*   rp  = pred + (size_t)row * C;
        const floatx4* rp4 = (const floatx4*)rp;

        floatx4 v[CHUNKS];
        #pragma unroll
        for (int j = 0; j < CHUNKS; ++j)
            v[j] = __builtin_nontemporal_load(&rp4[lane + j * 64]); // coalesced, nt
        const float pt = __builtin_nontemporal_load(&rp[(t < 0) ? 0 : t]);

        // prefetch next row's scalars (latency hides under this row's compute)
        const int nrow = row + nw;
        if (nrow < N) { t_nxt = tgt[nrow]; kn_nxt = known[nrow]; un_nxt = unknown[nrow]; }

        // row max
        float m = -INFINITY;
        #pragma unroll
        for (int j = 0; j < CHUNKS; ++j)
            m = fmaxf(m, fmaxf(fmaxf(v[j].x, v[j].y), fmaxf(v[j].z, v[j].w)));
        #pragma unroll
        for (int off = 32; off >= 1; off >>= 1)
            m = fmaxf(m, __shfl_xor(m, off, 64));

        // sum exp(x - m)
        float s = 0.0f;
        #pragma unroll
        for (int j = 0; j < CHUNKS; ++j) {
            s += __expf(v[j].x - m);
            s += __expf(v[j].y - m);
            s += __expf(v[j].z - m);
            s += __expf(v[j].w - m);
        }
        #pragma unroll
        for (int off = 32; off >= 1; off >>= 1)
            s += __shfl_xor(s, off, 64);

        const float logp = pt - m - __logf(s);
        const float p    = __expf(logp);
        const float term = logp * kn + __logf(1.0f - p + EPS) * un;

        if (lane == 0 && t != IGNORE_INDEX) {
            localSum += (double)term;
            localCnt += 1.0;
        }
    }

    // block reduce (only lane 0 of each wave holds nonzero) -> private ws slot
    __shared__ double sS[8];
    __shared__ double sC[8];
    if (lane == 0) { sS[wave] = localSum; sC[wave] = localCnt; }
    __syncthreads();
    if (threadIdx.x == 0) {
        double a = 0.0, b = 0.0;
        for (int i = 0; i < wpb; ++i) { a += sS[i]; b += sC[i]; }
        ws[2 * blockIdx.x]     = a;   // plain stores, no atomics
        ws[2 * blockIdx.x + 1] = b;
    }
}

// Generic fallback for arbitrary C (two passes over the row; L1/L2-backed).
__global__ __launch_bounds__(256) void ce_ul_generic(
    const float* __restrict__ pred,
    const int*   __restrict__ tgt,
    const float* __restrict__ known,
    const float* __restrict__ unknown,
    double*      __restrict__ ws,
    int N, int C)
{
    const int lane  = threadIdx.x & 63;
    const int wave  = threadIdx.x >> 6;
    const int wpb   = blockDim.x >> 6;
    const int gwave = blockIdx.x * wpb + wave;
    const int nw    = gridDim.x * wpb;

    double localSum = 0.0;
    double localCnt = 0.0;

    for (int row = gwave; row < N; row += nw) {
        const float* rp = pred + (size_t)row * C;
        float m = -INFINITY;
        for (int c = lane; c < C; c += 64) m = fmaxf(m, rp[c]);
        for (int off = 32; off >= 1; off >>= 1)
            m = fmaxf(m, __shfl_xor(m, off, 64));
        float s = 0.0f;
        for (int c = lane; c < C; c += 64) s += __expf(rp[c] - m);
        for (int off = 32; off >= 1; off >>= 1)
            s += __shfl_xor(s, off, 64);
        int t = tgt[row];
        if (lane == 0 && t != IGNORE_INDEX) {
            float pt   = rp[t];
            float logp = pt - m - __logf(s);
            float p    = __expf(logp);
            float term = logp * known[row] + __logf(1.0f - p + EPS) * unknown[row];
            localSum += (double)term;
            localCnt += 1.0;
        }
    }

    __shared__ double sS[8];
    __shared__ double sC[8];
    if (lane == 0) { sS[wave] = localSum; sC[wave] = localCnt; }
    __syncthreads();
    if (threadIdx.x == 0) {
        double a = 0.0, b = 0.0;
        for (int i = 0; i < wpb; ++i) { a += sS[i]; b += sC[i]; }
        ws[2 * blockIdx.x]     = a;
        ws[2 * blockIdx.x + 1] = b;
    }
}

// Single-block final reduce of per-block partials.
__global__ __launch_bounds__(256) void ce_ul_final(const double* __restrict__ ws,
                                                   float* __restrict__ out,
                                                   int nblocks)
{
    const int tid = threadIdx.x;
    double a = 0.0, b = 0.0;
    for (int i = tid; i < nblocks; i += 256) {
        a += ws[2 * i];
        b += ws[2 * i + 1];
    }
    for (int off = 32; off >= 1; off >>= 1) {
        a += __shfl_xor(a, off, 64);
        b += __shfl_xor(b, off, 64);
    }
    __shared__ double sA[4];
    __shared__ double sB[4];
    const int lane = tid & 63, wave = tid >> 6;
    if (lane == 0) { sA[wave] = a; sB[wave] = b; }
    __syncthreads();
    if (tid == 0) {
        double ta = sA[0] + sA[1] + sA[2] + sA[3];
        double tb = sB[0] + sB[1] + sB[2] + sB[3];
        out[0] = (float)(-ta / tb);
    }
}

extern "C" void kernel_launch(void* const* d_in, const int* in_sizes, int n_in,
                              void* d_out, int out_size, void* d_ws, size_t ws_size,
                              hipStream_t stream) {
    const float* pred    = (const float*)d_in[0];
    const int*   tgt     = (const int*)d_in[1];
    const float* known   = (const float*)d_in[2];
    const float* unknown = (const float*)d_in[3];
    float*       out     = (float*)d_out;
    double*      ws      = (double*)d_ws;

    const int N = in_sizes[1];
    const int C = in_sizes[0] / N;

    const int blocks = 2048;   // 8192 waves, grid-stride over N rows
    if (C == 1024) {
        hipLaunchKernelGGL((ce_ul_main<4>), dim3(blocks), dim3(256), 0, stream,
                           pred, tgt, known, unknown, ws, N);
    } else {
        hipLaunchKernelGGL(ce_ul_generic, dim3(blocks), dim3(256), 0, stream,
                           pred, tgt, known, unknown, ws, N, C);
    }

    hipLaunchKernelGGL(ce_ul_final, dim3(1), dim3(256), 0, stream,
                       ws, out, blocks);
}